// Round 17
// baseline (1762.255 us; speedup 1.0000x reference)
//
#include <hip/hip_runtime.h>
#include <hip/hip_bf16.h>

typedef __hip_bfloat16 bf16;
typedef __attribute__((ext_vector_type(8))) short bf16x8;
typedef __attribute__((ext_vector_type(4))) float f32x4;
typedef __attribute__((ext_vector_type(4))) int i32x4;

#define HH 300     // hidden (logical)
#define HP 320     // padded row length of msg/amsg buffers (640B = 10 lines)
#define NMOLS 2000
#define AFD 133    // atom feature dim
#define BFD 147    // bond feature dim
#define KP 480     // padded K of WT buffers
#define GOFS 160   // tail region starts at k=160
#define NWT (320 * KP)
#define FBP 160    // padded bf16 feature row length

// ---- direct global->LDS: dest = wave-uniform base + lane*16 ----
__device__ inline void gll16(short* lds_base, const void* gsrc) {
  auto l = (__attribute__((address_space(3))) short*)lds_base;
  auto g = (const __attribute__((address_space(1))) char*)gsrc;
  __builtin_amdgcn_global_load_lds(g, l, 16, 0, 0);
}

// counted vmcnt; cases {5,25}; default = full drain (conservative)
__device__ __forceinline__ void vwait(int n) {
  switch (n) {
    case 5:  asm volatile("s_waitcnt vmcnt(5)"  ::: "memory"); break;
    case 25: asm volatile("s_waitcnt vmcnt(25)" ::: "memory"); break;
    default: asm volatile("s_waitcnt vmcnt(0)"  ::: "memory"); break;
  }
}

// ---- build WT[c][k] bf16: k<fd -> W0[k][c]; 160<=k<460 -> W1[k-160][c]; else 0 ----
__global__ void build_wt(const float* __restrict__ W0, const float* __restrict__ W1,
                         int fd, bf16* __restrict__ WT)
{
  int idx = blockIdx.x * 256 + threadIdx.x;
  if (idx >= NWT) return;
  int c = idx / KP, k = idx - c * KP;
  float v = 0.f;
  if (c < HH) {
    if (k < fd) v = W0[(size_t)k * HH + c];
    else if (k >= GOFS && k < GOFS + HH) v = W1[(size_t)(k - GOFS) * HH + c];
  }
  WT[idx] = __float2bfloat16(v);
}

// ---- pad/convert features: Y[r][0..159] = bf16(X[r][0..fd-1]) | zeros ----
__global__ __launch_bounds__(256)
void cvt_pad(const float* __restrict__ X, int fd, bf16* __restrict__ Y, int N)
{
  int idx = blockIdx.x * 256 + threadIdx.x;
  if (idx >= N * 20) return;
  int rr = idx / 20, c8 = (idx - rr * 20) * 8;
  short t[8];
#pragma unroll
  for (int j = 0; j < 8; j++) {
    int c = c8 + j;
    float v = (c < fd) ? X[(size_t)rr * fd + c] : 0.f;
    union { bf16 b; short s; } cv; cv.b = __float2bfloat16(v); t[j] = cv.s;
  }
  *(bf16x8*)(Y + (size_t)rr * FBP + c8) = *(const bf16x8*)t;
}

// ---- amsg[a][k] = sum_j msg[a2b[a][j]][k]; 8 elems/thread, 16B-aligned uint4 ----
__global__ __launch_bounds__(256)
void gather6_k(const bf16* __restrict__ msg, const int* __restrict__ a2b,
               bf16* __restrict__ amsg, int A)
{
  int idx = blockIdx.x * 256 + threadIdx.x;
  if (idx >= A * 40) return;
  int a = idx / 40;
  int k8 = (idx - a * 40) * 8;
  bf16* dst = amsg + (size_t)a * HP + k8;
  if (k8 >= 304) {                    // pure pad: zeros
    uint4 z = {0, 0, 0, 0};
    *(uint4*)dst = z;
    return;
  }
  const int* p = a2b + (size_t)a * 6;
  uint4 u[6];
#pragma unroll
  for (int j = 0; j < 6; j++)
    u[j] = *(const uint4*)(msg + (size_t)p[j] * HP + k8);
  float s[8] = {0.f,0.f,0.f,0.f,0.f,0.f,0.f,0.f};
#pragma unroll
  for (int j = 0; j < 6; j++) {
    unsigned w[4] = {u[j].x, u[j].y, u[j].z, u[j].w};
#pragma unroll
    for (int q2 = 0; q2 < 4; q2++) {
      union { unsigned u; float f; } lo, hi;
      lo.u = w[q2] << 16;
      hi.u = w[q2] & 0xffff0000u;
      s[2 * q2]     += lo.f;
      s[2 * q2 + 1] += hi.f;
    }
  }
  if (k8 == 296) { s[4] = s[5] = s[6] = s[7] = 0.f; }
  short t[8];
#pragma unroll
  for (int j = 0; j < 8; j++) {
    union { bf16 b; short sh; } cv; cv.b = __float2bfloat16(s[j]); t[j] = cv.sh;
  }
  *(uint4*)dst = *(const uint4*)t;
}

// ============ single-stream slab gll MFMA GEMM: 64 rows x 320 cols, 4 waves ============
// Alternating-stream restructure: every step has ONE A-stream and 20 MFMAs.
//   MODE 0 (K=5):  s0-4 fbb                      -> msg = relu(C), row0=0
//   MODE 1 (K=25): s0-4 fbb | s5-14 amsg[b2a] | s15-24 -msg[b2revb] (WT rows reused)
//                                                -> msg = relu(C), row0=0
//   MODE 2 (K=15): s0-4 fab | s5-14 amsg[row]    -> hid = bf16(relu(C + bias))
// Slabs of 5 steps, LDS ring 2 (40KB max) -> with <=170 regs targets 3 blocks/CU.
// Uniform ledger: 5 glls/slab; vwait(25) per boundary (5 at s=0).
template<int MODE>
__global__ __launch_bounds__(256, 3)
void gemm_g(const bf16* __restrict__ FB, const bf16* __restrict__ WT,
            const int* __restrict__ b2a, const int* __restrict__ b2revb,
            const bf16* __restrict__ amsg, const bf16* __restrict__ msgc,
            const float* __restrict__ bias,
            bf16* __restrict__ msg_out, bf16* __restrict__ hid_out, int M)
{
  constexpr int KSTEPS = (MODE == 0) ? 5 : (MODE == 1) ? 25 : 15;
  constexpr int S = KSTEPS / 5;                 // slab count
  constexpr int NS = (S > 1) ? 2 : 1;           // LDS ring depth

  __shared__ __align__(16) short As[NS * 5 * 2048];   // [buf][step][64 rows][64B]

  const int tid = threadIdx.x;
  const int lane = tid & 63;
  const int wave = tid >> 6;
  const int gm0 = blockIdx.x * 64;

  // staging map: wave stages rows [wave*16, wave*16+16); LDS dest linear (gll),
  // swizzle on SOURCE k-chunk; read side applies the same XOR.
  const int lrow = wave * 16 + (lane >> 2);
  const int ssl = (lane & 3) ^ ((lrow >> 1) & 3);
  const int grow = min(gm0 + lrow, M - 1);      // clamped (stores guarded)
  int ba = 0, rb = 0;
  if constexpr (MODE == 1) { ba = b2a[grow]; rb = b2revb[grow]; }

  // compute map
  const int r = lane & 15, q = lane >> 4;
  int aoff[4];
#pragma unroll
  for (int i = 0; i < 4; i++) {
    int rr = i * 16 + r;
    aoff[i] = rr * 32 + ((q ^ (rr >> 1)) & 3) * 8;
  }
  const bf16* bb = WT + (size_t)(wave * 80 + r) * KP + q * 8;

  f32x4 acc[4][5];
#pragma unroll
  for (int i = 0; i < 4; i++)
#pragma unroll
    for (int j = 0; j < 5; j++) acc[i][j] = (f32x4){0.f, 0.f, 0.f, 0.f};

  bf16x8 bufB[2][5];                            // ring 2, distance-1
  auto issueB = [&](int s) {
    const int kb = (MODE == 1 && s >= 15) ? (s - 10) * 32 : s * 32;  // WT reuse
#pragma unroll
    for (int j = 0; j < 5; j++)
      bufB[s & 1][j] = *(const bf16x8*)(bb + (size_t)j * 16 * KP + kb);
  };

  // slab fetch: 5 adjacent line-aligned 64B chunks of this wave's row (one stream)
  auto issueSlab = [&](int slab) {
    short* la = &As[(slab % NS) * 5 * 2048 + wave * 512];
    const bf16* src;
    if (slab == 0) {
      src = FB + (size_t)grow * FBP;
    } else if constexpr (MODE == 1) {
      if (slab <= 2) src = amsg + (size_t)ba * HP + (slab - 1) * 160;
      else           src = msgc + (size_t)rb * HP + (slab - 3) * 160;
    } else {  // MODE 2
      src = amsg + (size_t)grow * HP + (slab - 1) * 160;
    }
#pragma unroll
    for (int c = 0; c < 5; c++)
      gll16(la + c * 2048, src + c * 32 + ssl * 8);
  };

  auto computeS = [&](int s) {
    const int buf = (s / 5) % NS, c = s % 5;
    const short* ca = &As[(buf * 5 + c) * 2048];
    bf16x8 af[4];
#pragma unroll
    for (int i = 0; i < 4; i++) af[i] = *(const bf16x8*)(ca + aoff[i]);
    if constexpr (MODE == 1) {
      if (s >= 15) {                            // negated msgc stream
#pragma unroll
        for (int i = 0; i < 4; i++) {
          union { bf16x8 h; i32x4 w; } u;
          u.h = af[i];
          u.w = u.w ^ (int)0x80008000;          // bf16 sign-flip
          af[i] = u.h;
        }
      }
    }
    __builtin_amdgcn_s_setprio(1);
#pragma unroll
    for (int j = 0; j < 5; j++)
#pragma unroll
      for (int i = 0; i < 4; i++)
        acc[i][j] = __builtin_amdgcn_mfma_f32_16x16x32_bf16(af[i], bufB[s & 1][j], acc[i][j], 0, 0, 0);
    __builtin_amdgcn_s_setprio(0);
  };

  // ---- prologue: B0, Gs0, Gs1  (order defines the vmcnt ledger) ----
  issueB(0);
  __builtin_amdgcn_sched_barrier(0);
  issueSlab(0);
  if (S > 1) issueSlab(1);
  __builtin_amdgcn_sched_barrier(0);

  // ---- main loop: vwait+barrier per slab; Gs(k+1) issued right after barrier ----
#pragma unroll
  for (int s = 0; s < KSTEPS; s++) {
    if (s % 5 == 0) {
      __builtin_amdgcn_sched_barrier(0);
      vwait(s == 0 ? (S > 1 ? 5 : 0) : 25);
      __builtin_amdgcn_s_barrier();
      __builtin_amdgcn_sched_barrier(0);
      const int nslab = s / 5 + 1;
      if (s > 0 && nslab < S) {
        issueSlab(nslab);
        __builtin_amdgcn_sched_barrier(0);      // pin: Gs before following B
      }
    }
    if (s + 1 < KSTEPS) issueB(s + 1);
    computeS(s);
  }

  // ---- epilogue: C/D frag col=lane&15, row=(lane>>4)*4+reg; write all 320 cols ----
#pragma unroll
  for (int j = 0; j < 5; j++) {
    int c = wave * 80 + j * 16 + r;             // < 320 always
    const bool pad = (c >= HH);
    float bia = (MODE == 2 && !pad) ? bias[c] : 0.f;
#pragma unroll
    for (int i = 0; i < 4; i++) {
#pragma unroll
      for (int ri = 0; ri < 4; ri++) {
        int g = gm0 + i * 16 + q * 4 + ri;
        if (g >= M) continue;
        float v = pad ? 0.f : acc[i][j][ri];
        if (MODE == 2) {
          hid_out[(size_t)g * HP + c] = __float2bfloat16(fmaxf(v + bia, 0.f));
        } else {
          float rv = fmaxf(v, 0.f);
          if (g == 0 || pad) rv = 0.f;
          msg_out[(size_t)g * HP + c] = __float2bfloat16(rv);
        }
      }
    }
  }
}

// per-molecule mean over sorted mol_id (binary search, no atomics); hid bf16, HP stride
__global__ void readout_k(const bf16* __restrict__ hid, const int* __restrict__ mol_id,
                          float* __restrict__ out, int A)
{
  __shared__ int bnd[2];
  int m = blockIdx.x;
  if (threadIdx.x < 2) {
    int target = m + (int)threadIdx.x;
    int lo = 0, hi = A;
    while (lo < hi) { int mid = (lo + hi) >> 1; if (mol_id[mid] < target) lo = mid + 1; else hi = mid; }
    bnd[threadIdx.x] = lo;
  }
  __syncthreads();
  int s = bnd[0], e = bnd[1];
  int h = threadIdx.x;
  if (h >= HH) return;
  float acc = 0.f;
  for (int a = s; a < e; a++) acc += __bfloat162float(hid[(size_t)a * HP + h]);
  int cnt = e - s; if (cnt < 1) cnt = 1;
  out[(size_t)m * HH + h] = acc / (float)cnt;
}

extern "C" void kernel_launch(void* const* d_in, const int* in_sizes, int n_in,
                              void* d_out, int out_size, void* d_ws, size_t ws_size,
                              hipStream_t stream)
{
  const float* f_atoms[2] = {(const float*)d_in[0], (const float*)d_in[2]};
  const float* f_bonds[2] = {(const float*)d_in[1], (const float*)d_in[3]};
  const float* W_i[2]     = {(const float*)d_in[4], (const float*)d_in[5]};
  const float* W_h[2]     = {(const float*)d_in[6], (const float*)d_in[7]};
  const float* W_o[2]     = {(const float*)d_in[8], (const float*)d_in[10]};
  const float* b_o[2]     = {(const float*)d_in[9], (const float*)d_in[11]};
  const int* a2b[2]    = {(const int*)d_in[12], (const int*)d_in[16]};
  const int* b2a[2]    = {(const int*)d_in[13], (const int*)d_in[17]};
  const int* b2revb[2] = {(const int*)d_in[14], (const int*)d_in[18]};
  const int* mol_id[2] = {(const int*)d_in[15], (const int*)d_in[19]};
  const int A = in_sizes[0] / AFD;   // 100001
  const int B = in_sizes[1] / BFD;   // 200001

  // ws: M0 | M1 (hid overlays) | amsg | fbb | fab | 4x WT  (~417 MB, proven)
  auto al = [](size_t x){ return (x + 255) & ~(size_t)255; };
  size_t r0 = al((size_t)B * HP * sizeof(bf16));
  size_t r1 = al((size_t)B * HP * sizeof(bf16));
  size_t amsz = al((size_t)A * HP * sizeof(bf16));
  size_t fbbsz = al((size_t)B * FBP * sizeof(bf16));
  size_t fabsz = al((size_t)A * FBP * sizeof(bf16));
  size_t wtsz = al((size_t)NWT * sizeof(bf16));
  if (ws_size < r0 + r1 + amsz + fbbsz + fabsz + 4 * wtsz) return;

  char* ws = (char*)d_ws;
  bf16*  M0  = (bf16*)ws;
  bf16*  M1  = (bf16*)(ws + r0);
  bf16*  hid = (bf16*)(ws + r0);            // overlays M1 region (bf16, A*HP)
  bf16*  amsg = (bf16*)(ws + r0 + r1);
  bf16*  fbb  = (bf16*)(ws + r0 + r1 + amsz);
  bf16*  fab  = (bf16*)(ws + r0 + r1 + amsz + fbbsz);
  size_t wofs = r0 + r1 + amsz + fbbsz + fabsz;
  bf16* WT1[2] = {(bf16*)(ws + wofs),            (bf16*)(ws + wofs + wtsz)};
  bf16* WT2[2] = {(bf16*)(ws + wofs + 2 * wtsz), (bf16*)(ws + wofs + 3 * wtsz)};

  dim3 blk(256);
  dim3 gW((NWT + 255) / 256);
  dim3 gB((B + 63) / 64);
  dim3 gA((A + 63) / 64);
  dim3 gG((A * 40 + 255) / 256);

  for (int p = 0; p < 2; p++) {
    build_wt<<<gW, blk, 0, stream>>>(W_i[p], W_h[p], BFD, WT1[p]);
    build_wt<<<gW, blk, 0, stream>>>(W_o[p], W_o[p] + (size_t)AFD * HH, AFD, WT2[p]);
  }

  for (int p = 0; p < 2; p++) {
    float* out_p = (float*)d_out + (size_t)p * NMOLS * HH;
    cvt_pad<<<(B * 20 + 255) / 256, blk, 0, stream>>>(f_bonds[p], BFD, fbb, B);
    cvt_pad<<<(A * 20 + 255) / 256, blk, 0, stream>>>(f_atoms[p], AFD, fab, A);
    // msg(M0) = relu(fbb @ W_i), row0=0
    gemm_g<0><<<gB, blk, 0, stream>>>(fbb, WT1[p], nullptr, nullptr,
                                      nullptr, nullptr, nullptr, M0, nullptr, B);
    // iter 1: amsg = gather6(M0); M1 = relu(fbb@Wi + amsg[b2a]@Wh - M0[b2revb]@Wh)
    gather6_k<<<gG, blk, 0, stream>>>(M0, a2b[p], amsg, A);
    gemm_g<1><<<gB, blk, 0, stream>>>(fbb, WT1[p], b2a[p], b2revb[p],
                                      amsg, M0, nullptr, M1, nullptr, B);
    // iter 2
    gather6_k<<<gG, blk, 0, stream>>>(M1, a2b[p], amsg, A);
    gemm_g<1><<<gB, blk, 0, stream>>>(fbb, WT1[p], b2a[p], b2revb[p],
                                      amsg, M1, nullptr, M0, nullptr, B);
    // output layer: hid(bf16) = relu([fab | gather6(M0)]@Wo + b)  (overlays M1)
    gather6_k<<<gG, blk, 0, stream>>>(M0, a2b[p], amsg, A);
    gemm_g<2><<<gA, blk, 0, stream>>>(fab, WT2[p], nullptr, nullptr,
                                      amsg, nullptr, b_o[p], nullptr, hid, A);
    // per-molecule mean readout
    readout_k<<<NMOLS, 320, 0, stream>>>(hid, mol_id[p], out_p, A);
  }
}

// Round 18
// 1583.330 us; speedup vs baseline: 1.1130x; 1.1130x over previous
//
#include <hip/hip_runtime.h>
#include <hip/hip_bf16.h>

typedef __hip_bfloat16 bf16;
typedef __attribute__((ext_vector_type(8))) short bf16x8;
typedef __attribute__((ext_vector_type(4))) float f32x4;
typedef __attribute__((ext_vector_type(4))) int i32x4;

#define HH 300     // hidden (logical)
#define HP 320     // padded row length of msg/amsg buffers (640B = 10 lines)
#define NMOLS 2000
#define AFD 133    // atom feature dim
#define BFD 147    // bond feature dim
#define KP 480     // padded K of WT buffers (15 steps of 32)
#define GOFS 160   // tail region starts at k=160 (step 5)
#define NWT (320 * KP)
#define FBP 160    // padded bf16 feature row length

// ---- direct global->LDS: dest = wave-uniform base + lane*16 ----
__device__ inline void gll16(short* lds_base, const void* gsrc) {
  auto l = (__attribute__((address_space(3))) short*)lds_base;
  auto g = (const __attribute__((address_space(1))) char*)gsrc;
  __builtin_amdgcn_global_load_lds(g, l, 16, 0, 0);
}

// counted vmcnt; cases cover {5,10,20,25}; default = full drain (conservative:
// correctness never depends on constant folding)
__device__ __forceinline__ void vwait(int n) {
  switch (n) {
    case 5:  asm volatile("s_waitcnt vmcnt(5)"  ::: "memory"); break;
    case 10: asm volatile("s_waitcnt vmcnt(10)" ::: "memory"); break;
    case 20: asm volatile("s_waitcnt vmcnt(20)" ::: "memory"); break;
    case 25: asm volatile("s_waitcnt vmcnt(25)" ::: "memory"); break;
    default: asm volatile("s_waitcnt vmcnt(0)"  ::: "memory"); break;
  }
}

// ---- build WT[c][k] bf16: k<fd -> W0[k][c]; 160<=k<460 -> W1[k-160][c]; else 0 ----
// Zero pads load-bearing: A-tail reads cols 300..319 (buffer pad, zeroed) against
// WT rows k>=460 (zero), and feature pad k in [fd,160) (zero).
__global__ void build_wt(const float* __restrict__ W0, const float* __restrict__ W1,
                         int fd, bf16* __restrict__ WT)
{
  int idx = blockIdx.x * 256 + threadIdx.x;
  if (idx >= NWT) return;
  int c = idx / KP, k = idx - c * KP;
  float v = 0.f;
  if (c < HH) {
    if (k < fd) v = W0[(size_t)k * HH + c];
    else if (k >= GOFS && k < GOFS + HH) v = W1[(size_t)(k - GOFS) * HH + c];
  }
  WT[idx] = __float2bfloat16(v);
}

// ---- pad/convert features: Y[r][0..159] = bf16(X[r][0..fd-1]) | zeros ----
__global__ __launch_bounds__(256)
void cvt_pad(const float* __restrict__ X, int fd, bf16* __restrict__ Y, int N)
{
  int idx = blockIdx.x * 256 + threadIdx.x;
  if (idx >= N * 20) return;
  int rr = idx / 20, c8 = (idx - rr * 20) * 8;
  short t[8];
#pragma unroll
  for (int j = 0; j < 8; j++) {
    int c = c8 + j;
    float v = (c < fd) ? X[(size_t)rr * fd + c] : 0.f;
    union { bf16 b; short s; } cv; cv.b = __float2bfloat16(v); t[j] = cv.s;
  }
  *(bf16x8*)(Y + (size_t)rr * FBP + c8) = *(const bf16x8*)t;
}

// ---- amsg[a][k] = sum_j msg[a2b[a][j]][k]; 8 elems/thread, 16B-aligned uint4 ----
// 40 threads/row cover the full 320-elem padded row; cols >=300 written as zero.
__global__ __launch_bounds__(256)
void gather6_k(const bf16* __restrict__ msg, const int* __restrict__ a2b,
               bf16* __restrict__ amsg, int A)
{
  int idx = blockIdx.x * 256 + threadIdx.x;
  if (idx >= A * 40) return;
  int a = idx / 40;
  int k8 = (idx - a * 40) * 8;
  bf16* dst = amsg + (size_t)a * HP + k8;
  if (k8 >= 304) {                    // pure pad: zeros
    uint4 z = {0, 0, 0, 0};
    *(uint4*)dst = z;
    return;
  }
  const int* p = a2b + (size_t)a * 6;
  uint4 u[6];
#pragma unroll
  for (int j = 0; j < 6; j++)
    u[j] = *(const uint4*)(msg + (size_t)p[j] * HP + k8);   // 16B aligned (HP row)
  float s[8] = {0.f,0.f,0.f,0.f,0.f,0.f,0.f,0.f};
#pragma unroll
  for (int j = 0; j < 6; j++) {
    unsigned w[4] = {u[j].x, u[j].y, u[j].z, u[j].w};
#pragma unroll
    for (int q2 = 0; q2 < 4; q2++) {
      union { unsigned u; float f; } lo, hi;
      lo.u = w[q2] << 16;
      hi.u = w[q2] & 0xffff0000u;
      s[2 * q2]     += lo.f;
      s[2 * q2 + 1] += hi.f;
    }
  }
  if (k8 == 296) { s[4] = s[5] = s[6] = s[7] = 0.f; }  // cols 300..303 -> 0
  short t[8];
#pragma unroll
  for (int j = 0; j < 8; j++) {
    union { bf16 b; short sh; } cv; cv.b = __float2bfloat16(s[j]); t[j] = cv.sh;
  }
  *(uint4*)dst = *(const uint4*)t;
}

// ============ slab-fetch gll MFMA GEMM: 64 rows x 320 cols, 4 waves split N ============
// K = 3 slabs x 5 steps (MODE0: 1 slab). Per slab each wave issues its row as
// 5 ADJACENT line-aligned glls (320B burst per random 640B-padded row). One
// barrier per slab. Issue order: B before G (B-waits never retire glls).
// MODE 0: C = fbb@Wi (5 steps);                          msg = relu(C), row0=0
// MODE 1: C = fbb@Wi + amsg[b2a]@Wh + (-msg[b2revb])@Wh; msg = relu(C), row0=0
// MODE 2: C = [fab | amsg]@Wo;                           hid = bf16(relu(C + bias))
// Epilogue writes ALL 320 cols (pad=0): full-line stores + pads stay zero.
template<int MODE>
__global__ __launch_bounds__(256)
void gemm_g(const bf16* __restrict__ FB, const bf16* __restrict__ WT,
            const int* __restrict__ b2a, const int* __restrict__ b2revb,
            const bf16* __restrict__ amsg, const bf16* __restrict__ msgc,
            const float* __restrict__ bias,
            bf16* __restrict__ msg_out, bf16* __restrict__ hid_out, int M)
{
  constexpr int KSTEPS = (MODE == 0) ? 5 : 15;
  constexpr bool DUAL = (MODE == 1);
  constexpr int NSLAB = (MODE == 0) ? 1 : 2;          // slab ring depth
  // vmcnt ledger:
  //   slab0 wait: newer than Gs0 = Gs1 glls        -> MODE1:10  MODE2:5  MODE0:0
  //   slab1 wait: newer than Gs1 = B2..B6          -> 25
  //   slab2 wait: newer than Gs2 = B8..B11         -> 20
  constexpr int W0C = (MODE == 1) ? 10 : (MODE == 2) ? 5 : 0;

  __shared__ __align__(16) short As[NSLAB * 5 * 2048];          // per step-slot 4KB
  __shared__ __align__(16) short Ms[DUAL ? NSLAB * 5 * 2048 : 16];

  const int tid = threadIdx.x;
  const int lane = tid & 63;
  const int wave = tid >> 6;
  const int gm0 = blockIdx.x * 64;

  // staging map: wave stages rows [wave*16, wave*16+16); LDS dest linear (gll),
  // swizzle applied on SOURCE k-chunk; read side applies same XOR.
  const int lrow = wave * 16 + (lane >> 2);
  const int ssl = (lane & 3) ^ ((lrow >> 1) & 3);
  const int grow = min(gm0 + lrow, M - 1);   // clamped (stores guarded)
  int ba = 0, rb = 0;
  if constexpr (DUAL) { ba = b2a[grow]; rb = b2revb[grow]; }

  // compute map
  const int r = lane & 15, q = lane >> 4;
  int aoff[4];
#pragma unroll
  for (int i = 0; i < 4; i++) {
    int rr = i * 16 + r;
    aoff[i] = rr * 32 + ((q ^ (rr >> 1)) & 3) * 8;
  }
  const bf16* bb = WT + (size_t)(wave * 80 + r) * KP + q * 8;

  f32x4 acc[4][5];
#pragma unroll
  for (int i = 0; i < 4; i++)
#pragma unroll
    for (int j = 0; j < 5; j++) acc[i][j] = (f32x4){0.f, 0.f, 0.f, 0.f};

  bf16x8 bufB[3][5];                 // ring of 3, distance-2 prefetch
  auto issueB = [&](int s) {
#pragma unroll
    for (int j = 0; j < 5; j++)
      bufB[s % 3][j] = *(const bf16x8*)(bb + (size_t)j * 16 * KP + s * 32);
  };

  // slab fetch: 5 adjacent LINE-ALIGNED 64B chunks of this wave's row(s)
  auto issueSlab = [&](int slab) {
    const int buf = slab % NSLAB;
    short* la = &As[buf * 5 * 2048 + wave * 512];
    if (slab == 0) {                 // head: feature row (exactly FBP*2 = 320B)
#pragma unroll
      for (int c = 0; c < 5; c++)
        gll16(la + c * 2048, FB + (size_t)grow * FBP + c * 32 + ssl * 8);
    } else {
      const int k0 = (slab - 1) * 160;   // tail k offset: slab1->0, slab2->160
      if constexpr (DUAL) {
#pragma unroll
        for (int c = 0; c < 5; c++)
          gll16(la + c * 2048, amsg + (size_t)ba * HP + k0 + c * 32 + ssl * 8);
        short* lm = &Ms[buf * 5 * 2048 + wave * 512];
#pragma unroll
        for (int c = 0; c < 5; c++)
          gll16(lm + c * 2048, msgc + (size_t)rb * HP + k0 + c * 32 + ssl * 8);
      } else {  // MODE 2
#pragma unroll
        for (int c = 0; c < 5; c++)
          gll16(la + c * 2048, amsg + (size_t)grow * HP + k0 + c * 32 + ssl * 8);
      }
    }
  };

  auto computeS = [&](int s) {
    const int buf = (s / 5) % NSLAB, c = s % 5;
    const short* ca = &As[(buf * 5 + c) * 2048];
    bf16x8 af[4];
#pragma unroll
    for (int i = 0; i < 4; i++) af[i] = *(const bf16x8*)(ca + aoff[i]);
    bf16x8 mfn[4];
    if constexpr (DUAL) {
      if (s >= 5) {
        const short* cm = &Ms[(buf * 5 + c) * 2048];
#pragma unroll
        for (int i = 0; i < 4; i++) {
          union { bf16x8 h; i32x4 w; } u;
          u.h = *(const bf16x8*)(cm + aoff[i]);
          u.w = u.w ^ (int)0x80008000;    // bf16 sign-flip: (-msg)@Wh
          mfn[i] = u.h;
        }
      }
    }
    __builtin_amdgcn_s_setprio(1);
#pragma unroll
    for (int j = 0; j < 5; j++)
#pragma unroll
      for (int i = 0; i < 4; i++) {
        acc[i][j] = __builtin_amdgcn_mfma_f32_16x16x32_bf16(af[i], bufB[s % 3][j], acc[i][j], 0, 0, 0);
        if constexpr (DUAL) {
          if (s >= 5)
            acc[i][j] = __builtin_amdgcn_mfma_f32_16x16x32_bf16(mfn[i], bufB[s % 3][j], acc[i][j], 0, 0, 0);
        }
      }
    __builtin_amdgcn_s_setprio(0);
  };

  // ---- prologue: B0, B1, Gs0, Gs1  (B BEFORE G: B-waits never retire glls) ----
  issueB(0);
  issueB(1);
  issueSlab(0);
  if (KSTEPS > 5) issueSlab(1);
  __builtin_amdgcn_sched_barrier(0);

  // ---- main loop: one vwait+barrier per slab; Gs2 issued after barrier@5 ----
#pragma unroll
  for (int s = 0; s < KSTEPS; s++) {
    if (s % 5 == 0) {
      __builtin_amdgcn_sched_barrier(0);   // pin: no B-issue sinks below the wait
      vwait(s == 0 ? W0C : (s == 5 ? 25 : 20));
      __builtin_amdgcn_s_barrier();
      __builtin_amdgcn_sched_barrier(0);
    }
    if (s + 2 < KSTEPS) issueB(s + 2);
    if (s == 5) {                          // issue slab2 (consumed at s=10)
      __builtin_amdgcn_sched_barrier(0);   // pin: B7 before Gs2
      issueSlab(2);
      __builtin_amdgcn_sched_barrier(0);   // pin: B8.. after Gs2
    }
    computeS(s);
  }

  // ---- epilogue: C/D frag col=lane&15, row=(lane>>4)*4+reg; write all 320 cols ----
#pragma unroll
  for (int j = 0; j < 5; j++) {
    int c = wave * 80 + j * 16 + r;        // < 320 always
    const bool pad = (c >= HH);
    float bia = (MODE == 2 && !pad) ? bias[c] : 0.f;
#pragma unroll
    for (int i = 0; i < 4; i++) {
#pragma unroll
      for (int ri = 0; ri < 4; ri++) {
        int g = gm0 + i * 16 + q * 4 + ri;
        if (g >= M) continue;
        float v = pad ? 0.f : acc[i][j][ri];
        if (MODE == 2) {
          hid_out[(size_t)g * HP + c] = __float2bfloat16(fmaxf(v + bia, 0.f));
        } else {
          float rv = fmaxf(v, 0.f);
          if (g == 0 || pad) rv = 0.f;
          msg_out[(size_t)g * HP + c] = __float2bfloat16(rv);
        }
      }
    }
  }
}

// per-molecule mean over sorted mol_id (binary search, no atomics); hid bf16, HP stride
__global__ void readout_k(const bf16* __restrict__ hid, const int* __restrict__ mol_id,
                          float* __restrict__ out, int A)
{
  __shared__ int bnd[2];
  int m = blockIdx.x;
  if (threadIdx.x < 2) {
    int target = m + (int)threadIdx.x;
    int lo = 0, hi = A;
    while (lo < hi) { int mid = (lo + hi) >> 1; if (mol_id[mid] < target) lo = mid + 1; else hi = mid; }
    bnd[threadIdx.x] = lo;
  }
  __syncthreads();
  int s = bnd[0], e = bnd[1];
  int h = threadIdx.x;
  if (h >= HH) return;
  float acc = 0.f;
  for (int a = s; a < e; a++) acc += __bfloat162float(hid[(size_t)a * HP + h]);
  int cnt = e - s; if (cnt < 1) cnt = 1;
  out[(size_t)m * HH + h] = acc / (float)cnt;
}

extern "C" void kernel_launch(void* const* d_in, const int* in_sizes, int n_in,
                              void* d_out, int out_size, void* d_ws, size_t ws_size,
                              hipStream_t stream)
{
  const float* f_atoms[2] = {(const float*)d_in[0], (const float*)d_in[2]};
  const float* f_bonds[2] = {(const float*)d_in[1], (const float*)d_in[3]};
  const float* W_i[2]     = {(const float*)d_in[4], (const float*)d_in[5]};
  const float* W_h[2]     = {(const float*)d_in[6], (const float*)d_in[7]};
  const float* W_o[2]     = {(const float*)d_in[8], (const float*)d_in[10]};
  const float* b_o[2]     = {(const float*)d_in[9], (const float*)d_in[11]};
  const int* a2b[2]    = {(const int*)d_in[12], (const int*)d_in[16]};
  const int* b2a[2]    = {(const int*)d_in[13], (const int*)d_in[17]};
  const int* b2revb[2] = {(const int*)d_in[14], (const int*)d_in[18]};
  const int* mol_id[2] = {(const int*)d_in[15], (const int*)d_in[19]};
  const int A = in_sizes[0] / AFD;   // 100001
  const int B = in_sizes[1] / BFD;   // 200001

  // ws: M0 | M1 (hid overlays) | amsg | fbb | fab | 4x WT  (~417 MB <= 422 proven)
  auto al = [](size_t x){ return (x + 255) & ~(size_t)255; };
  size_t r0 = al((size_t)B * HP * sizeof(bf16));
  size_t r1 = al((size_t)B * HP * sizeof(bf16));
  size_t amsz = al((size_t)A * HP * sizeof(bf16));
  size_t fbbsz = al((size_t)B * FBP * sizeof(bf16));
  size_t fabsz = al((size_t)A * FBP * sizeof(bf16));
  size_t wtsz = al((size_t)NWT * sizeof(bf16));
  if (ws_size < r0 + r1 + amsz + fbbsz + fabsz + 4 * wtsz) return;

  char* ws = (char*)d_ws;
  bf16*  M0  = (bf16*)ws;
  bf16*  M1  = (bf16*)(ws + r0);
  bf16*  hid = (bf16*)(ws + r0);            // overlays M1 region (bf16, A*HP)
  bf16*  amsg = (bf16*)(ws + r0 + r1);
  bf16*  fbb  = (bf16*)(ws + r0 + r1 + amsz);
  bf16*  fab  = (bf16*)(ws + r0 + r1 + amsz + fbbsz);
  size_t wofs = r0 + r1 + amsz + fbbsz + fabsz;
  bf16* WT1[2] = {(bf16*)(ws + wofs),            (bf16*)(ws + wofs + wtsz)};
  bf16* WT2[2] = {(bf16*)(ws + wofs + 2 * wtsz), (bf16*)(ws + wofs + 3 * wtsz)};

  dim3 blk(256);
  dim3 gW((NWT + 255) / 256);
  dim3 gB((B + 63) / 64);
  dim3 gA((A + 63) / 64);
  dim3 gG((A * 40 + 255) / 256);

  for (int p = 0; p < 2; p++) {
    build_wt<<<gW, blk, 0, stream>>>(W_i[p], W_h[p], BFD, WT1[p]);
    build_wt<<<gW, blk, 0, stream>>>(W_o[p], W_o[p] + (size_t)AFD * HH, AFD, WT2[p]);
  }

  for (int p = 0; p < 2; p++) {
    float* out_p = (float*)d_out + (size_t)p * NMOLS * HH;
    cvt_pad<<<(B * 20 + 255) / 256, blk, 0, stream>>>(f_bonds[p], BFD, fbb, B);
    cvt_pad<<<(A * 20 + 255) / 256, blk, 0, stream>>>(f_atoms[p], AFD, fab, A);
    // msg(M0) = relu(fbb @ W_i), row0=0  (pads zeroed by epilogue)
    gemm_g<0><<<gB, blk, 0, stream>>>(fbb, WT1[p], nullptr, nullptr,
                                      nullptr, nullptr, nullptr, M0, nullptr, B);
    // iter 1: amsg = gather6(M0); M1 = relu(fbb@Wi + amsg[b2a]@Wh - M0[b2revb]@Wh)
    gather6_k<<<gG, blk, 0, stream>>>(M0, a2b[p], amsg, A);
    gemm_g<1><<<gB, blk, 0, stream>>>(fbb, WT1[p], b2a[p], b2revb[p],
                                      amsg, M0, nullptr, M1, nullptr, B);
    // iter 2
    gather6_k<<<gG, blk, 0, stream>>>(M1, a2b[p], amsg, A);
    gemm_g<1><<<gB, blk, 0, stream>>>(fbb, WT1[p], b2a[p], b2revb[p],
                                      amsg, M1, nullptr, M0, nullptr, B);
    // output layer: hid(bf16) = relu([fab | gather6(M0)]@Wo + b)  (overlays M1)
    gather6_k<<<gG, blk, 0, stream>>>(M0, a2b[p], amsg, A);
    gemm_g<2><<<gA, blk, 0, stream>>>(fab, WT2[p], nullptr, nullptr,
                                      amsg, nullptr, b_o[p], nullptr, hid, A);
    // per-molecule mean readout
    readout_k<<<NMOLS, 320, 0, stream>>>(hid, mol_id[p], out_p, A);
  }
}